// Round 2
// baseline (151.195 us; speedup 1.0000x reference)
//
#include <hip/hip_runtime.h>

// KAN layer as one fused fp16 MFMA GEMM:
//   out[b,i] = sum_j [ neg*bw*pw + pos*bw + sum_k basis[b,j,k]*sw[i,j]*sc[i,j,k] ]
// A  [2048 x 11264] fp16 : per j, 22 slots = {20 basis (5 nonzero), neg, pos}
// Ct [ 512 x 11264] fp16 : per j, 22 slots = {sw*sc[0..19], bw*pw, bw}   (B^T layout)
// GEMM: 128x128 tiles, mfma_f32_16x16x32_f16, global_load_lds(16B), splitK=8 + f32 atomics.
// ws usage: A = 46.1 MB, Ct = 11.5 MB (57.7 MB total).
// If ws_size < needed: zero-workspace fused fallback (slow but correct).

typedef _Float16 half_t;
typedef __attribute__((ext_vector_type(8))) _Float16 half8;
typedef __attribute__((ext_vector_type(4))) float floatx4;

#define B_DIM   2048
#define J_DIM   512
#define O_DIM   512
#define SLOTS   22
#define K_TOT   (J_DIM * SLOTS)      // 11264
#define MTILE   128
#define NTILE   128
#define BK      32
#define KSPLIT  8
#define KS_LEN  (K_TOT / KSPLIT)     // 1408
#define KCH     (KS_LEN / BK)        // 44

// ---------------------------------------------------------------------------
// Quartic B-spline local basis, uniform knots g_i = -1.5 + i*(3.125/24).
// (Reference quirk: linspace(-1.5, 1.625, 25) -> spacing 3.125/24, NOT 0.125.)
// Matches reference De Boor recursion; m in [3,19]; window k = m-4 .. m,
// entries with k<0 dropped (truncated family, as in the reference).
__device__ __forceinline__ void bspline5(float xc, int& k0, float Nv[5]) {
    const float invS = 7.68f;              // 24/3.125 (exact ratio)
    float u = (xc + 1.5f) * invS;          // knot units
    int m = (int)u;
    m = min(max(m, 3), 19);
    k0 = m - 4;
    Nv[0] = 1.f; Nv[1] = 0.f; Nv[2] = 0.f; Nv[3] = 0.f; Nv[4] = 0.f;
#pragma unroll
    for (int d = 1; d <= 4; ++d) {
        float nw[5];
        float inv_d = 1.0f / (float)d;
#pragma unroll
        for (int r = 0; r < 5; ++r) {
            if (r > d) { nw[r] = 0.f; continue; }
            float kk = (float)(m - d + r);
            float acc = 0.f;
            if (r >= 1) acc += (u - kk) * Nv[r - 1];
            if (r < d)  acc += (kk + (float)(d + 1) - u) * Nv[r];
            nw[r] = acc * inv_d;
        }
#pragma unroll
        for (int r = 0; r < 5; ++r) Nv[r] = nw[r];
    }
}

// ---------------------------------------------------------------------------
// prep_A: one block per b-row; 512 records of 22 fp16 each, staged in LDS,
// stored as contiguous uint4s (coalesced).
__global__ __launch_bounds__(256) void prep_A(const float* __restrict__ x,
                                              half_t* __restrict__ A) {
    __shared__ half_t rec[J_DIM * SLOTS];  // 22528 B
    int b = blockIdx.x;
    int t = threadIdx.x;
#pragma unroll
    for (int jj = 0; jj < 2; ++jj) {
        int j = t + jj * 256;
        float xv = x[(size_t)b * J_DIM + j];
        float xc = fminf(fmaxf(xv, -1.f), 1.f);
        float pos = fmaxf(xc, 0.f);
        float neg = xc - pos;
        int k0; float Nv[5];
        bspline5(xc, k0, Nv);
        half_t* r = rec + j * SLOTS;
#pragma unroll
        for (int k = 0; k < 20; ++k) r[k] = (half_t)0.f;
#pragma unroll
        for (int rr = 0; rr < 5; ++rr) {
            int k = k0 + rr;
            if (k >= 0) r[k] = (half_t)Nv[rr];   // k <= 19 guaranteed (k0 <= 15)
        }
        r[20] = (half_t)neg;
        r[21] = (half_t)pos;
    }
    __syncthreads();
    const uint4* src = (const uint4*)rec;
    uint4* dst = (uint4*)(A + (size_t)b * K_TOT);
    for (int i = t; i < (J_DIM * SLOTS * 2) / 16; i += 256) dst[i] = src[i];
}

// ---------------------------------------------------------------------------
// prep_C: one block per out-row i; fold spline_weight into coeffs + base slots.
__global__ __launch_bounds__(256) void prep_C(const float* __restrict__ pw,
                                              const float* __restrict__ bw,
                                              const float* __restrict__ sw,
                                              const float* __restrict__ sc,
                                              half_t* __restrict__ Ct) {
    __shared__ half_t rec[J_DIM * SLOTS];
    int i = blockIdx.x;
    int t = threadIdx.x;
#pragma unroll
    for (int jj = 0; jj < 2; ++jj) {
        int j = t + jj * 256;
        size_t ij = (size_t)i * J_DIM + j;
        float s = sw[ij], b = bw[ij], p = pw[ij];
        const float* scp = sc + ij * 20;
        half_t* r = rec + j * SLOTS;
#pragma unroll
        for (int k = 0; k < 20; ++k) r[k] = (half_t)(s * scp[k]);
        r[20] = (half_t)(b * p);
        r[21] = (half_t)b;
    }
    __syncthreads();
    const uint4* src = (const uint4*)rec;
    uint4* dst = (uint4*)(Ct + (size_t)i * K_TOT);
    for (int idx = t; idx < (J_DIM * SLOTS * 2) / 16; idx += 256) dst[idx] = src[idx];
}

// ---------------------------------------------------------------------------
// GEMM: m97-style. Grid (16, 4, 8) = (m-blocks, n-blocks, k-splits), 256 thr.
__global__ __launch_bounds__(256) void gemm_f16(const half_t* __restrict__ A,
                                                const half_t* __restrict__ Bt,
                                                float* __restrict__ out) {
    __shared__ half_t As[MTILE * BK];   // 8 KB
    __shared__ half_t Bs[NTILE * BK];   // 8 KB

    int m0 = blockIdx.x * MTILE;
    int n0 = blockIdx.y * NTILE;
    int ks = blockIdx.z * KS_LEN;

    int t = threadIdx.x;
    int w = t >> 6;          // wave 0..3
    int l = t & 63;
    int wm = w >> 1, wn = w & 1;

    floatx4 acc[4][4] = {};

    int lrow = l >> 2;            // 0..15
    int lkof = (l & 3) * 8;       // fp16 element offset within BK row

    const half_t* gA = A + (size_t)m0 * K_TOT + ks;
    const half_t* gB = Bt + (size_t)n0 * K_TOT + ks;

    int q = l >> 4;               // 0..3
    int fr = l & 15;              // 0..15

    for (int c = 0; c < KCH; ++c) {
        int kb = c * BK;
#pragma unroll
        for (int n = 0; n < 2; ++n) {
            int r = (w * 2 + n) * 16 + lrow;
            __builtin_amdgcn_global_load_lds(
                (const __attribute__((address_space(1))) unsigned int*)
                    (gA + (size_t)r * K_TOT + kb + lkof),
                (__attribute__((address_space(3))) unsigned int*)
                    (As + (w * 2 + n) * 512),
                16, 0, 0);
            __builtin_amdgcn_global_load_lds(
                (const __attribute__((address_space(1))) unsigned int*)
                    (gB + (size_t)r * K_TOT + kb + lkof),
                (__attribute__((address_space(3))) unsigned int*)
                    (Bs + (w * 2 + n) * 512),
                16, 0, 0);
        }
        __syncthreads();

        half8 af[4], bf[4];
#pragma unroll
        for (int mt = 0; mt < 4; ++mt)
            af[mt] = *(const half8*)(As + (wm * 64 + mt * 16 + fr) * BK + q * 8);
#pragma unroll
        for (int nt = 0; nt < 4; ++nt)
            bf[nt] = *(const half8*)(Bs + (wn * 64 + nt * 16 + fr) * BK + q * 8);
#pragma unroll
        for (int mt = 0; mt < 4; ++mt)
#pragma unroll
            for (int nt = 0; nt < 4; ++nt)
                acc[mt][nt] = __builtin_amdgcn_mfma_f32_16x16x32_f16(
                    af[mt], bf[nt], acc[mt][nt], 0, 0, 0);
        __syncthreads();
    }

    // epilogue: C/D layout col = lane&15, row = (lane>>4)*4 + reg (m89-verified)
#pragma unroll
    for (int mt = 0; mt < 4; ++mt)
#pragma unroll
        for (int nt = 0; nt < 4; ++nt) {
            int rr = m0 + wm * 64 + mt * 16 + q * 4;
            int cc = n0 + wn * 64 + nt * 16 + fr;
#pragma unroll
            for (int r = 0; r < 4; ++r)
                atomicAdd(out + (size_t)(rr + r) * O_DIM + cc, acc[mt][nt][r]);
        }
}

// ---------------------------------------------------------------------------
// Zero-workspace fallback: one block per batch row b. Basis staged in LDS,
// direct 5-coefficient gather from sc. Correct but slow (~hundreds of µs);
// only taken if ws_size is too small for the GEMM path.
__global__ __launch_bounds__(256) void kan_fallback(const float* __restrict__ x,
                                                    const float* __restrict__ pw,
                                                    const float* __restrict__ bw,
                                                    const float* __restrict__ sw,
                                                    const float* __restrict__ sc,
                                                    float* __restrict__ out) {
    __shared__ float s_neg[J_DIM], s_pos[J_DIM], s_bas[J_DIM][5];
    __shared__ int s_k0[J_DIM];
    int b = blockIdx.x;
    int t = threadIdx.x;
#pragma unroll
    for (int jj = 0; jj < 2; ++jj) {
        int j = t + jj * 256;
        float xv = x[(size_t)b * J_DIM + j];
        float xc = fminf(fmaxf(xv, -1.f), 1.f);
        float pos = fmaxf(xc, 0.f);
        s_pos[j] = pos;
        s_neg[j] = xc - pos;
        int k0; float Nv[5];
        bspline5(xc, k0, Nv);
        s_k0[j] = k0;
#pragma unroll
        for (int r = 0; r < 5; ++r) s_bas[j][r] = Nv[r];
    }
    __syncthreads();
    for (int i = t; i < O_DIM; i += 256) {
        float acc = 0.f;
        for (int j = 0; j < J_DIM; ++j) {
            size_t ij = (size_t)i * J_DIM + j;
            float bwv = bw[ij];
            acc += bwv * (pw[ij] * s_neg[j] + s_pos[j]);
            int k0 = s_k0[j];
            const float* cp = sc + ij * 20;
            float sp = 0.f;
#pragma unroll
            for (int r = 0; r < 5; ++r) {
                int k = k0 + r;
                if (k >= 0) sp += s_bas[j][r] * cp[k];
            }
            acc += sw[ij] * sp;
        }
        out[(size_t)b * O_DIM + i] = acc;
    }
}

// ---------------------------------------------------------------------------
extern "C" void kernel_launch(void* const* d_in, const int* in_sizes, int n_in,
                              void* d_out, int out_size, void* d_ws, size_t ws_size,
                              hipStream_t stream) {
    const float* x  = (const float*)d_in[0];
    const float* pw = (const float*)d_in[1];
    const float* bw = (const float*)d_in[2];
    const float* sw = (const float*)d_in[3];
    const float* sc = (const float*)d_in[4];
    float* out = (float*)d_out;

    const size_t ws_needed = (size_t)(B_DIM + O_DIM) * K_TOT * sizeof(half_t); // 57.7 MB
    if (ws_size < ws_needed) {
        kan_fallback<<<B_DIM, 256, 0, stream>>>(x, pw, bw, sw, sc, out);
        return;
    }

    half_t* A  = (half_t*)d_ws;
    half_t* Ct = A + (size_t)B_DIM * K_TOT;

    hipMemsetAsync(d_out, 0, (size_t)out_size * sizeof(float), stream);
    prep_A<<<B_DIM, 256, 0, stream>>>(x, A);
    prep_C<<<O_DIM, 256, 0, stream>>>(pw, bw, sw, sc, Ct);
    dim3 g(B_DIM / MTILE, O_DIM / NTILE, KSPLIT);   // (16, 4, 8)
    gemm_f16<<<g, 256, 0, stream>>>(A, Ct, out);
}